// Round 2
// baseline (1470.457 us; speedup 1.0000x reference)
//
#include <hip/hip_runtime.h>

typedef _Float16 f16;
typedef _Float16 f16x2 __attribute__((ext_vector_type(2)));
typedef _Float16 f16x8 __attribute__((ext_vector_type(8)));
typedef float f32x4 __attribute__((ext_vector_type(4)));
typedef unsigned int u32;

#define SEQ   512
#define BATCH 256
#define INS   58
#define INP   64          // padded input width
#define HID   256
#define NCAT  18
#define G3    (3*HID)     // 768
#define TC    128         // timestep chunk
#define NCHUNK (SEQ/TC)   // 4
#define MC    (TC*BATCH)  // 32768 rows per chunk

// ---------------------------------------------------------------- dot2 helper
__device__ __forceinline__ float fdot2f(u32 a, u32 b, float c) {
#if __has_builtin(__builtin_amdgcn_fdot2)
  return __builtin_amdgcn_fdot2(__builtin_bit_cast(f16x2, a),
                                __builtin_bit_cast(f16x2, b), c, false);
#else
  f16x2 av = __builtin_bit_cast(f16x2, a);
  f16x2 bv = __builtin_bit_cast(f16x2, b);
  return c + (float)av[0] * (float)bv[0] + (float)av[1] * (float)bv[1];
#endif
}

// ------------------------------------------------------- f32 -> f16 (pad cols)
__global__ void k_convert_pad(const float* __restrict__ src, f16* __restrict__ dst,
                              int rows, int scols, int dcols) {
  int i = blockIdx.x * blockDim.x + threadIdx.x;
  int total = rows * dcols;
  if (i >= total) return;
  int r = i / dcols, c = i - r * dcols;
  float v = (c < scols) ? src[(size_t)r * scols + c] : 0.f;
  dst[i] = (f16)v;
}

// --------------------------------------------------------------- f16 MFMA GEMM
// out[M][768] = A[M][K] * W[768][K]^T + bias.  128x128 tile, BK=32, 4 waves.
#define BM 128
#define BN 128
#define BK 32
#define LDP 40   // padded LDS pitch (f16 elems)

__global__ __launch_bounds__(256, 2)
void k_gemm_f16(const f16* __restrict__ A, const f16* __restrict__ W,
                const float* __restrict__ bias, f16* __restrict__ out,
                int K) {
  __shared__ __align__(16) f16 As[BM][LDP];
  __shared__ __align__(16) f16 Ws[BN][LDP];
  const int tid  = threadIdx.x;
  const int lane = tid & 63;
  const int wave = tid >> 6;            // 0..3
  const int wm = wave >> 1, wn = wave & 1;
  const int n0 = blockIdx.x * BN;       // grid.x = 6
  const int m0 = blockIdx.y * BM;       // grid.y = MC/BM

  f32x4 acc[4][4] = {};

  for (int k0 = 0; k0 < K; k0 += BK) {
    __syncthreads();
#pragma unroll
    for (int c = 0; c < 2; ++c) {
      int j   = c * 256 + tid;          // 0..511
      int row = j >> 2;                 // 0..127
      int kc  = j & 3;                  // 16B chunk within 32-col row
      uint4 va = *(const uint4*)(A + (size_t)(m0 + row) * K + k0 + kc * 8);
      *(uint4*)(&As[row][kc * 8]) = va;
      uint4 vw = *(const uint4*)(W + (size_t)(n0 + row) * K + k0 + kc * 8);
      *(uint4*)(&Ws[row][kc * 8]) = vw;
    }
    __syncthreads();
    const int rsel = lane & 15;
    const int ks   = (lane >> 4) * 8;
    f16x8 af[4], bf[4];
#pragma unroll
    for (int i = 0; i < 4; ++i)
      af[i] = *(const f16x8*)(&As[wm * 64 + i * 16 + rsel][ks]);
#pragma unroll
    for (int j = 0; j < 4; ++j)
      bf[j] = *(const f16x8*)(&Ws[wn * 64 + j * 16 + rsel][ks]);
#pragma unroll
    for (int i = 0; i < 4; ++i)
#pragma unroll
      for (int j = 0; j < 4; ++j)
        acc[i][j] = __builtin_amdgcn_mfma_f32_16x16x32_f16(af[i], bf[j], acc[i][j], 0, 0, 0);
  }

#pragma unroll
  for (int j = 0; j < 4; ++j) {
    int col = n0 + wn * 64 + j * 16 + (lane & 15);
    float bv = bias[col];
#pragma unroll
    for (int i = 0; i < 4; ++i) {
      int rbase = m0 + wm * 64 + i * 16 + ((lane >> 4) << 2);
#pragma unroll
      for (int rr = 0; rr < 4; ++rr)
        out[(size_t)(rbase + rr) * G3 + col] = (f16)(acc[i][j][rr] + bv);
    }
  }
}

// ------------------------------------------------------ persistent GRU layer
// One workgroup (512 threads) per batch element. W_hh held in VGPRs as f16
// pairs: thread (k2, r) owns gate rows {r, 256+r, 512+r}, K-cols [k2*128,+128).
// Processes TC timesteps; h carried across chunks in hstate (f32).
template <int FINAL>
__global__ __launch_bounds__(512, 2)
void k_gru(const f16* __restrict__ gx,     // [MC][768], includes b_ih
           const f16* __restrict__ Whh,    // [768][256] f16
           const float* __restrict__ bhh,  // [768]
           f16* __restrict__ hout,         // [MC][256] or nullptr
           float* __restrict__ hstate,     // [BATCH][256] f32 carry
           int first, int last,
           const float* __restrict__ fcw,  // [18][256]  (FINAL only)
           const float* __restrict__ fcb,  // [18]
           float* __restrict__ out) {      // [256][18]
  const int b   = blockIdx.x;
  const int tid = threadIdx.x;
  const int k2  = tid >> 8;   // 0/1 : K half
  const int r   = tid & 255;  // hidden index

  __shared__ __align__(16) f16 hsh[HID];
  __shared__ float psum[G3];

  // ---- load recurrent weights into registers (192 VGPRs of packed f16) ----
  u32 w0[64], w1[64], w2[64];
  {
    const f16* base = Whh + (size_t)k2 * 128;
#pragma unroll
    for (int c = 0; c < 16; ++c) {
      uint4 v0 = *(const uint4*)(base + (size_t)(0 * HID + r) * HID + c * 8);
      w0[c * 4 + 0] = v0.x; w0[c * 4 + 1] = v0.y; w0[c * 4 + 2] = v0.z; w0[c * 4 + 3] = v0.w;
      uint4 v1 = *(const uint4*)(base + (size_t)(1 * HID + r) * HID + c * 8);
      w1[c * 4 + 0] = v1.x; w1[c * 4 + 1] = v1.y; w1[c * 4 + 2] = v1.z; w1[c * 4 + 3] = v1.w;
      uint4 v2 = *(const uint4*)(base + (size_t)(2 * HID + r) * HID + c * 8);
      w2[c * 4 + 0] = v2.x; w2[c * 4 + 1] = v2.y; w2[c * 4 + 2] = v2.z; w2[c * 4 + 3] = v2.w;
    }
  }

  float bhr = 0.f, bhz = 0.f, bhn = 0.f;
  float hprev = 0.f;
  if (k2 == 0) {
    bhr = bhh[r]; bhz = bhh[HID + r]; bhn = bhh[2 * HID + r];
    hprev = first ? 0.f : hstate[(size_t)b * HID + r];
    hsh[r] = (f16)hprev;
  }

  // prefetch gx for t=0
  float gxr = 0.f, gxz = 0.f, gxn = 0.f;
  if (k2 == 0) {
    const f16* g0 = gx + ((size_t)0 * BATCH + b) * G3;
    gxr = (float)g0[r]; gxz = (float)g0[HID + r]; gxn = (float)g0[2 * HID + r];
  }
  __syncthreads();

  for (int t = 0; t < TC; ++t) {
    // prefetch next timestep's gx (used after the dot phase)
    float nxr = 0.f, nxz = 0.f, nxn = 0.f;
    if (k2 == 0 && t + 1 < TC) {
      const f16* gn = gx + ((size_t)(t + 1) * BATCH + b) * G3;
      nxr = (float)gn[r]; nxz = (float)gn[HID + r]; nxn = (float)gn[2 * HID + r];
    }

    // ---- dot phase: gh partials over this thread's K half ----
    float ar = 0.f, az = 0.f, an = 0.f;
    const uint4* hp = (const uint4*)(hsh + k2 * 128);
#pragma unroll
    for (int c = 0; c < 16; ++c) {
      uint4 v = hp[c];
      u32 h4[4] = {v.x, v.y, v.z, v.w};
#pragma unroll
      for (int q = 0; q < 4; ++q) {
        ar = fdot2f(w0[c * 4 + q], h4[q], ar);
        az = fdot2f(w1[c * 4 + q], h4[q], az);
        an = fdot2f(w2[c * 4 + q], h4[q], an);
      }
    }

    if (k2 == 1) { psum[r] = ar; psum[HID + r] = az; psum[2 * HID + r] = an; }
    __syncthreads();

    if (k2 == 0) {
      float ghr = ar + psum[r]           + bhr;
      float ghz = az + psum[HID + r]     + bhz;
      float ghn = an + psum[2 * HID + r] + bhn;
      float rg = 1.f / (1.f + __expf(-(gxr + ghr)));
      float zg = 1.f / (1.f + __expf(-(gxz + ghz)));
      float nt = gxn + rg * ghn;
      float e2 = __expf(-2.f * fabsf(nt));       // safe tanh
      float th = (1.f - e2) / (1.f + e2);
      float ng = (nt >= 0.f) ? th : -th;
      float hn = (1.f - zg) * ng + zg * hprev;
      hprev = hn;
      hsh[r] = (f16)hn;
      if (hout) hout[((size_t)t * BATCH + b) * HID + r] = (f16)hn;
      gxr = nxr; gxz = nxz; gxn = nxn;
    }
    __syncthreads();
  }

  if (k2 == 0) hstate[(size_t)b * HID + r] = hprev;

  if (FINAL) {
    if (last) {
      if (k2 == 0) psum[r] = hprev;
      __syncthreads();
      if (tid < NCAT) {
        float s = fcb[tid];
        for (int q = 0; q < HID; ++q) s += fcw[(size_t)tid * HID + q] * psum[q];
        out[(size_t)b * NCAT + tid] = s;
      }
    }
  }
}

// ---------------------------------------------------------------------- launch
extern "C" void kernel_launch(void* const* d_in, const int* in_sizes, int n_in,
                              void* d_out, int out_size, void* d_ws, size_t ws_size,
                              hipStream_t stream) {
  const float* x    = (const float*)d_in[0];
  const float* Wih0 = (const float*)d_in[1];
  const float* Whh0 = (const float*)d_in[2];
  const float* bih0 = (const float*)d_in[3];
  const float* bhh0 = (const float*)d_in[4];
  const float* Wih1 = (const float*)d_in[5];
  const float* Whh1 = (const float*)d_in[6];
  const float* bih1 = (const float*)d_in[7];
  const float* bhh1 = (const float*)d_in[8];
  const float* fcw  = (const float*)d_in[9];
  const float* fcb  = (const float*)d_in[10];
  float* out = (float*)d_out;

  // ---- workspace layout (~73 MB total) ----
  char* ws = (char*)d_ws;
  size_t off = 0;
  f16*   whh0h = (f16*)(ws + off); off += (size_t)G3 * HID * 2;      //   393,216
  f16*   whh1h = (f16*)(ws + off); off += (size_t)G3 * HID * 2;      //   393,216
  f16*   wih0h = (f16*)(ws + off); off += (size_t)G3 * INP * 2;      //    98,304
  f16*   wih1h = (f16*)(ws + off); off += (size_t)G3 * HID * 2;      //   393,216
  float* h0st  = (float*)(ws + off); off += (size_t)BATCH * HID * 4; //   262,144
  float* h1st  = (float*)(ws + off); off += (size_t)BATCH * HID * 4; //   262,144
  f16*   xhc   = (f16*)(ws + off); off += (size_t)MC * INP * 2;      // 4,194,304
  f16*   h0c   = (f16*)(ws + off); off += (size_t)MC * HID * 2;      // 16,777,216
  f16*   gxc   = (f16*)(ws + off); off += (size_t)MC * G3 * 2;       // 50,331,648
  // total ~73.1 MB

  // ---- one-time weight converts ----
  k_convert_pad<<<(G3 * INP + 255) / 256, 256, 0, stream>>>(Wih0, wih0h, G3, INS, INP);
  k_convert_pad<<<(G3 * HID + 255) / 256, 256, 0, stream>>>(Whh0, whh0h, G3, HID, HID);
  k_convert_pad<<<(G3 * HID + 255) / 256, 256, 0, stream>>>(Wih1, wih1h, G3, HID, HID);
  k_convert_pad<<<(G3 * HID + 255) / 256, 256, 0, stream>>>(Whh1, whh1h, G3, HID, HID);

  for (int c = 0; c < NCHUNK; ++c) {
    int first = (c == 0), last = (c == NCHUNK - 1);
    const float* xc = x + (size_t)c * MC * INS;

    // x chunk -> f16, pad 58 -> 64
    k_convert_pad<<<(MC * INP + 255) / 256, 256, 0, stream>>>(xc, xhc, MC, INS, INP);
    // gx0 = xh @ Wih0^T + b_ih0
    k_gemm_f16<<<dim3(G3 / BN, MC / BM), 256, 0, stream>>>(xhc, wih0h, bih0, gxc, INP);
    // layer-0 recurrence over this chunk
    k_gru<0><<<BATCH, 512, 0, stream>>>(gxc, whh0h, bhh0, h0c, h0st, first, last,
                                        nullptr, nullptr, nullptr);
    // gx1 = h0 @ Wih1^T + b_ih1 (reuse gxc; stream order serializes)
    k_gemm_f16<<<dim3(G3 / BN, MC / BM), 256, 0, stream>>>(h0c, wih1h, bih1, gxc, HID);
    // layer-1 recurrence (+ final FC on last chunk)
    k_gru<1><<<BATCH, 512, 0, stream>>>(gxc, whh1h, bhh1, nullptr, h1st, first, last,
                                        fcw, fcb, out);
  }
}